// Round 8
// baseline (275.405 us; speedup 1.0000x reference)
//
#include <hip/hip_runtime.h>

typedef __attribute__((ext_vector_type(8))) __bf16 bf16x8;
typedef __attribute__((ext_vector_type(4))) __bf16 bf16x4;
typedef __attribute__((ext_vector_type(16))) float f32x16;
typedef __attribute__((ext_vector_type(4))) float f32x4;
typedef __attribute__((ext_vector_type(4))) int i32x4;

#define HH 192
#define WW 192
#define HW 36864
#define HW1 36100

#define TCS 144                  // deform/pconv staged col pitch
#define RP66 (66 * TCS)          // pconv staging row pitch
#define GDNPITCH 144
#define TREG 8704                // transpose region: 32 px x 68 f32
#define TROW 5120                // tail-kernel LDS row pitch: 40 cols x 128B
#define NPREP 1417               // prep blocks in fused prologue kernel

__device__ inline f32x16 mfma32(bf16x8 a, bf16x8 b, f32x16 c) {
  return __builtin_amdgcn_mfma_f32_32x32x16_bf16(a, b, c, 0, 0, 0);
}

__device__ inline f32x16 zero16() {
  f32x16 z;
#pragma unroll
  for (int e = 0; e < 16; ++e) z[e] = 0.f;
  return z;
}

// ---------------- fused prologue: weight prep + NCHW->NHWC transpose ----------------
__global__ __launch_bounds__(256) void prep_and_nhwc(
    const float* __restrict__ wp, const float* __restrict__ bp,
    const float* __restrict__ wdc, const float* __restrict__ wcat,
    const float* __restrict__ w1, const float* __restrict__ w2,
    const float* __restrict__ gamma,
    __bf16* __restrict__ wpA, __bf16* __restrict__ wdcA,
    __bf16* __restrict__ wcatA, __bf16* __restrict__ w1A,
    __bf16* __restrict__ w2A, __bf16* __restrict__ gA,
    float* __restrict__ bpad,
    const float* __restrict__ fr, const float* __restrict__ mt,
    __bf16* __restrict__ frn, __bf16* __restrict__ mtn) {
  __shared__ __align__(16) __bf16 tile[64 * 72];
  if (blockIdx.x >= NPREP) {
    // -------- transpose path --------
    int rem2 = blockIdx.x - NPREP;
    int tensor = rem2 / 1152, rem = rem2 % 1152;
    int b = rem / 576, p0 = (rem % 576) * 64;
    const float* src = (tensor ? mt : fr) + (size_t)b * 64 * HW;
    __bf16* dst = (tensor ? mtn : frn) + (size_t)b * HW * 64;
    int tid = threadIdx.x, c = tid >> 2, q0 = (tid & 3) * 16;
    const float* sp = src + (size_t)c * HW + p0 + q0;
#pragma unroll
    for (int qq = 0; qq < 4; ++qq) {
      f32x4 v = *(const f32x4*)(sp + qq * 4);
#pragma unroll
      for (int e = 0; e < 4; ++e) tile[(q0 + qq * 4 + e) * 72 + c] = (__bf16)v[e];
    }
    __syncthreads();
    int px = tid >> 2, c0 = (tid & 3) * 16;
    bf16x8 a = *(const bf16x8*)(&tile[px * 72 + c0]);
    bf16x8 b8 = *(const bf16x8*)(&tile[px * 72 + c0 + 8]);
    __bf16* dp = dst + (size_t)(p0 + px) * 64 + c0;
    *(bf16x8*)dp = a;
    *(bf16x8*)(dp + 8) = b8;
    return;
  }
  // -------- weight-prep path --------
  int i = blockIdx.x * 256 + threadIdx.x;
  if (i < 18432) {
    int j = i & 7, lane = (i >> 3) & 63, kc = (i >> 9) & 3, n = i >> 11;
    int o = lane & 31, c = kc * 16 + ((lane >> 5) << 3) + j;
    wpA[i] = (o < 18) ? (__bf16)wp[(o * 64 + c) * 9 + n] : (__bf16)0.f;
    return;
  }
  i -= 18432;
  if (i < 36864) {
    int j = i & 7, lane = (i >> 3) & 63, ot = (i >> 9) & 1, kc = (i >> 10) & 3, n = i >> 12;
    int o = ot * 32 + (lane & 31), c = kc * 16 + ((lane >> 5) << 3) + j;
    wdcA[i] = (__bf16)wdc[(o * 64 + c) * 9 + n];
    return;
  }
  i -= 36864;
  if (i < 73728) {
    int d = i, j = d & 7; d >>= 3; int lane = d & 63; d >>= 6; int ot = d & 1; d >>= 1;
    int kc = d & 7; int n = d >> 3;
    int o = ot * 32 + (lane & 31), c = kc * 16 + ((lane >> 5) << 3) + j;
    wcatA[i] = (__bf16)wcat[(o * 128 + c) * 9 + n];
    return;
  }
  i -= 73728;
  if (i < 110592) {
    int l = i / 36864, di = i % 36864, d = di;
    int j = d & 7; d >>= 3; int lane = d & 63; d >>= 6; int ot = d & 1; d >>= 1;
    int kc = d & 3; int n = d >> 2;
    int o = ot * 32 + (lane & 31), c = kc * 16 + ((lane >> 5) << 3) + j;
    w1A[l * 36864 + di] = (__bf16)w1[l * 36864 + (o * 64 + c) * 9 + n];
    return;
  }
  i -= 110592;
  if (i < 110592) {
    int l = i / 36864, di = i % 36864, d = di;
    int j = d & 7; d >>= 3; int lane = d & 63; d >>= 6; int ot = d & 1; d >>= 1;
    int kc = d & 3; int n = d >> 2;
    int o = ot * 32 + (lane & 31), c = kc * 16 + ((lane >> 5) << 3) + j;
    w2A[l * 36864 + di] = (__bf16)w2[l * 36864 + (o * 64 + c) * 9 + n];
    return;
  }
  i -= 110592;
  if (i < 12288) {
    int l = i / 4096, di = i % 4096, d = di;
    int j = d & 7; d >>= 3; int lane = d & 63; d >>= 6; int ot = d & 1; d >>= 1;
    int kc = d & 3;
    int o = ot * 32 + (lane & 31), c = kc * 16 + ((lane >> 5) << 3) + j;
    gA[l * 4096 + di] = (__bf16)gamma[l * 4096 + o * 64 + c];
    return;
  }
  i -= 12288;
  // bpad[0..17] = pconv bias, bpad[18..95] = 0 (incl. 256B zero page at +32)
  if (i < 96) bpad[i] = (i < 18) ? bp[i] : 0.f;
}

// ---------------- staging loop (pconv only) ----------------
template <int ROWS, int COLS, int TPB>
__device__ inline void stage_bf16T(const __bf16* __restrict__ src,
                                   int srcH, int srcW, int row0, int col0,
                                   unsigned char* lds) {
  for (int i = threadIdx.x; i < ROWS * COLS * 8; i += TPB) {
    int r = i / (COLS * 8), rem = i - r * (COLS * 8), j = rem >> 3, u = rem & 7;
    int gr = row0 + r, gc = col0 + j;
    bf16x8 v;
#pragma unroll
    for (int e = 0; e < 8; ++e) v[e] = (__bf16)0.f;
    if (gr >= 0 && gr < srcH && gc >= 0 && gc < srcW)
      v = *(const bf16x8*)(src + ((size_t)gr * srcW + gc) * 64 + u * 8);
    *(bf16x8*)(lds + r * (COLS * TCS) + j * TCS + u * 16) = v;
  }
}

// ---- global_load_lds staging of one 1KB chunk (8 cols x 8 granules) ----
__device__ inline void stage_glds(const __bf16* __restrict__ src, int H, int W,
                                  int gr, int gc0, const __bf16* __restrict__ zpad,
                                  unsigned char* ldsrow, int chunk) {
  int l = threadIdx.x & 63;
  int colg = l >> 3, gsrc = (l & 7) ^ colg;
  int gc = gc0 + chunk * 8 + colg;
  const __bf16* gp = zpad;
  if (gr >= 0 && gr < H && gc >= 0 && gc < W)
    gp = src + ((size_t)gr * W + gc) * 64 + gsrc * 8;
  __builtin_amdgcn_global_load_lds(
      (const __attribute__((address_space(1))) void*)gp,
      (__attribute__((address_space(3))) void*)(ldsrow + chunk * 1024), 16, 0, 0);
}

// ---- per-wave tap: 32 out-ch (ot half) x 64 px (2 rows), B from swizzled LDS ----
template <int KCW>
__device__ inline void tapG(const __bf16* __restrict__ aB, int ot,
                            const unsigned char* __restrict__ tile,
                            int n, int koff, f32x16 acc[2]) {
  int lane = threadIdx.x & 63;
  int m = lane & 31, half = lane >> 5;
  int kh = n / 3, kw = n % 3;
  int p = kw + m, p7 = p & 7;
  bf16x8 A[4], B0[4], B1[4];
#pragma unroll
  for (int kc = 0; kc < 4; ++kc)
    A[kc] = *(const bf16x8*)(aB + (size_t)((n * KCW + koff + kc) * 2 + ot) * 512);
#pragma unroll
  for (int kc = 0; kc < 4; ++kc) {
    int gsl = ((kc * 2 + half) ^ p7) << 4;
    B0[kc] = *(const bf16x8*)(tile + (kh + 0) * TROW + p * 128 + gsl);
    B1[kc] = *(const bf16x8*)(tile + (kh + 1) * TROW + p * 128 + gsl);
  }
#pragma unroll
  for (int kc = 0; kc < 4; ++kc) {
    acc[0] = mfma32(A[kc], B0[kc], acc[0]);
    acc[1] = mfma32(A[kc], B1[kc], acc[1]);
  }
}

// ---- partial-acc merge via XOR-swizzled LDS (bank-conflict-free) ----
__device__ inline void merge_write(const f32x16 acc[2], unsigned char* mb) {
  int l = threadIdx.x & 63;
  unsigned char* p = mb + l * 128;
#pragma unroll
  for (int pt = 0; pt < 2; ++pt)
#pragma unroll
    for (int i = 0; i < 4; ++i) {
      f32x4 v;
      v[0] = acc[pt][i * 4 + 0]; v[1] = acc[pt][i * 4 + 1];
      v[2] = acc[pt][i * 4 + 2]; v[3] = acc[pt][i * 4 + 3];
      *(f32x4*)(p + (((pt * 4 + i) ^ (l & 7)) * 16)) = v;
    }
}
__device__ inline void merge_add(f32x16 acc[2], const unsigned char* mb) {
  int l = threadIdx.x & 63;
  const unsigned char* p = mb + l * 128;
#pragma unroll
  for (int pt = 0; pt < 2; ++pt)
#pragma unroll
    for (int i = 0; i < 4; ++i) {
      f32x4 v = *(const f32x4*)(p + (((pt * 4 + i) ^ (l & 7)) * 16));
      acc[pt][i * 4 + 0] += v[0]; acc[pt][i * 4 + 1] += v[1];
      acc[pt][i * 4 + 2] += v[2]; acc[pt][i * 4 + 3] += v[3];
    }
}

// ---- epilogue: write one row's (ot-half) acc into a shared transpose region ----
__device__ inline void treg_write(const f32x16& a, int ot, unsigned char* reg) {
  int lane = threadIdx.x & 63;
  int m = lane & 31, half = lane >> 5;
#pragma unroll
  for (int g = 0; g < 4; ++g) {
    int o = ot * 32 + half * 4 + g * 8;
    f32x4 v;
    v[0] = a[g * 4 + 0]; v[1] = a[g * 4 + 1];
    v[2] = a[g * 4 + 2]; v[3] = a[g * 4 + 3];
    *(f32x4*)(reg + (m * 68 + o) * 4) = v;
  }
}

// ---------------- deform epilogue helper ----------------
__device__ inline void acc32_to_lds(const f32x16 acc[2], unsigned char* reg) {
  int lane = threadIdx.x & 63;
  int colb = lane & 31, half = lane >> 5;
#pragma unroll
  for (int ot = 0; ot < 2; ++ot)
#pragma unroll
    for (int g = 0; g < 4; ++g) {
      int o = ot * 32 + half * 4 + g * 8;
      f32x4 v;
      v[0] = acc[ot][g * 4 + 0]; v[1] = acc[ot][g * 4 + 1];
      v[2] = acc[ot][g * 4 + 2]; v[3] = acc[ot][g * 4 + 3];
      *(f32x4*)(reg + (colb * 68 + o) * 4) = v;
    }
}

// ---------------- pconv MFMA (unchanged) ----------------
__global__ __launch_bounds__(256, 1) void pconv_mfma(
    const __bf16* __restrict__ mtn, const __bf16* __restrict__ wpA,
    const float* __restrict__ bpad, float* __restrict__ off20) {
  __shared__ __align__(16) unsigned char smem[6 * RP66];
  int b = blockIdx.x / 144, r = blockIdx.x % 144, rt = r / 3, ct = r % 3;
  int h0 = rt * 4, w0 = ct * 64;
  int wid = threadIdx.x >> 6, lane = threadIdx.x & 63;
  int colb = lane & 31, half = lane >> 5, kh8 = half << 3;
  stage_bf16T<6, 66, 256>(mtn + (size_t)b * HW * 64, 192, 192, h0 - 1, w0 - 1, smem);
  const __bf16* aB = wpA + lane * 8;
  bf16x8 pcur[4], pnxt[4];
#pragma unroll
  for (int kc = 0; kc < 4; ++kc) pcur[kc] = *(const bf16x8*)(aB + kc * 512);
  __syncthreads();
  f32x16 acc[2];
  acc[0] = zero16(); acc[1] = zero16();
  {
    const unsigned char* bB = smem + wid * RP66 + colb * TCS + kh8 * 2;
#pragma unroll
    for (int n = 0; n < 9; ++n) {
      if (n < 8) {
#pragma unroll
        for (int kc = 0; kc < 4; ++kc)
          pnxt[kc] = *(const bf16x8*)(aB + ((n + 1) * 4 + kc) * 512);
      }
      const int kh = n / 3, kw = n % 3;
#pragma unroll
      for (int kc = 0; kc < 4; ++kc) {
        const unsigned char* bp = bB + kh * RP66 + kw * TCS + kc * 32;
        bf16x8 b0 = *(const bf16x8*)(bp);
        bf16x8 b1 = *(const bf16x8*)(bp + 32 * TCS);
        acc[0] = mfma32(pcur[kc], b0, acc[0]);
        acc[1] = mfma32(pcur[kc], b1, acc[1]);
      }
#pragma unroll
      for (int kc = 0; kc < 4; ++kc) pcur[kc] = pnxt[kc];
    }
  }
  __syncthreads();
  unsigned char* reg = smem + wid * 9216;
#pragma unroll
  for (int pt = 0; pt < 2; ++pt)
#pragma unroll
    for (int g = 0; g < 4; ++g) {
      int o = half * 4 + g * 8;
      f32x4 v;
      v[0] = acc[pt][g * 4 + 0]; v[1] = acc[pt][g * 4 + 1];
      v[2] = acc[pt][g * 4 + 2]; v[3] = acc[pt][g * 4 + 3];
      *(f32x4*)(reg + ((pt * 32 + colb) * 36 + o) * 4) = v;
    }
  __builtin_amdgcn_s_waitcnt(0);
  size_t pix = (size_t)b * HW + (size_t)(h0 + wid) * 192 + w0 + lane;
#pragma unroll
  for (int q = 0; q < 5; ++q) {
    f32x4 v = *(const f32x4*)(reg + (lane * 36 + q * 4) * 4);
    v += *(const f32x4*)(bpad + q * 4);
    *(f32x4*)(off20 + pix * 20 + q * 4) = v;
  }
}

// ---------------- deformable conv: 4-wave tap-split + XOR LDS merge ----------------
#define GOPITCH 32
#define DTBL (9 * 32 * GOPITCH)   // 9216: g/idx table
#define DBUF 4608                 // 32 px x TCS blended tile per wave
#define DLDS (DTBL + 4 * DBUF)    // 27648
__global__ __launch_bounds__(256, 2) void deform_mfma(
    const __bf16* __restrict__ frn, const float* __restrict__ off20,
    const __bf16* __restrict__ wdcA, float* __restrict__ xlow,
    __bf16* __restrict__ xlowb) {
  __shared__ __align__(16) unsigned char smem[DLDS];
  int bid = (blockIdx.x & 7) * 288 + (blockIdx.x >> 3);
  int b = bid / 1152, r = bid % 1152;
  int h = r / 6, s = r % 6;
  int w0 = s * 32;
  int tid = threadIdx.x;
  int wid = tid >> 6, lane = tid & 63;
  int m = lane & 31, half = lane >> 5;
  int pxg = lane >> 3, slot = lane & 7;
  const __bf16* xb = frn + (size_t)b * HW * 64;
  // ---- offset prologue: 256 threads, 9 taps x 32 px ----
  {
    int px = tid & 31, g = tid >> 5;   // g = 0..7
    int w = w0 + px;
    size_t pixl = (size_t)b * HW + (size_t)h * 192 + w;
    const float* ofp = off20 + pixl * 20;
    for (int n = g; n < 9; n += 8) {
      float offr = ofp[n], offc = ofp[9 + n];
      float pr = (float)(h + 1 + n / 3 - 1) + offr;
      float pc = (float)(w + 1 + n % 3 - 1) + offc;
      float prc = fminf(fmaxf(pr, 0.f), 193.f);
      float pcc = fminf(fmaxf(pc, 0.f), 193.f);
      float f0r = floorf(pr), f0c = floorf(pc);
      int qr0 = (int)fminf(fmaxf(f0r, 0.f), 193.f);
      int qc0 = (int)fminf(fmaxf(f0c, 0.f), 193.f);
      int qr1 = (int)fminf(fmaxf(f0r + 1.f, 0.f), 193.f);
      int qc1 = (int)fminf(fmaxf(f0c + 1.f, 0.f), 193.f);
      float dr0 = 1.f + ((float)qr0 - prc);
      float dr1 = 1.f - ((float)qr1 - prc);
      float dc0 = 1.f + ((float)qc0 - pcc);
      float dc1 = 1.f - ((float)qc1 - pcc);
      int o0, o1, o2, o3; float g0, g1, g2, g3;
      { bool v = (qr0 >= 1 && qr0 <= 192 && qc0 >= 1 && qc0 <= 192);
        o0 = min(max(qr0-1,0),191)*WW + min(max(qc0-1,0),191); g0 = v ? dr0*dc0 : 0.f; }
      { bool v = (qr1 >= 1 && qr1 <= 192 && qc1 >= 1 && qc1 <= 192);
        o1 = min(max(qr1-1,0),191)*WW + min(max(qc1-1,0),191); g1 = v ? dr1*dc1 : 0.f; }
      { bool v = (qr0 >= 1 && qr0 <= 192 && qc1 >= 1 && qc1 <= 192);
        o2 = min(max(qr0-1,0),191)*WW + min(max(qc1-1,0),191); g2 = v ? dr0*dc1 : 0.f; }
      { bool v = (qr1 >= 1 && qr1 <= 192 && qc0 >= 1 && qc0 <= 192);
        o3 = min(max(qr1-1,0),191)*WW + min(max(qc0-1,0),191); g3 = v ? dr1*dc0 : 0.f; }
      unsigned char* dst = smem + (n * 32 + px) * GOPITCH;
      f32x4 gv; gv[0] = g0; gv[1] = g1; gv[2] = g2; gv[3] = g3;
      i32x4 ov; ov[0] = o0; ov[1] = o1; ov[2] = o2; ov[3] = o3;
      *(f32x4*)dst = gv;
      *(i32x4*)(dst + 16) = ov;
    }
  }
  __syncthreads();
  f32x16 acc[2];
  acc[0] = zero16(); acc[1] = zero16();
  const __bf16* aB = wdcA + lane * 8;
  unsigned char* buf = smem + DTBL + wid * DBUF;
  const unsigned char* bB = buf + m * TCS + (half << 3) * 2;
  // tap split: wave0: 0-2, wave1: 3-4, wave2: 5-6, wave3: 7-8
  int n0 = (wid == 0) ? 0 : (wid * 2 + 1);
  int nn = (wid == 0) ? 3 : 2;

  bf16x8 C[4][4];
  f32x4 G[4];
  bf16x8 a[8];

  auto load_tap = [&](int n) {
#pragma unroll
    for (int i = 0; i < 4; ++i) {
      const unsigned char* gp = smem + (size_t)(n * 32 + i * 8 + pxg) * GOPITCH;
      i32x4 oi = *(const i32x4*)(gp + 16);
      G[i] = *(const f32x4*)gp;
#pragma unroll
      for (int j = 0; j < 4; ++j)
        C[i][j] = *(const bf16x8*)(xb + (size_t)oi[j] * 64 + slot * 8);
    }
  };
  auto load_a = [&](int n) {
#pragma unroll
    for (int kc = 0; kc < 4; ++kc) {
      a[kc * 2 + 0] = *(const bf16x8*)(aB + ((n * 4 + kc) * 2 + 0) * 512);
      a[kc * 2 + 1] = *(const bf16x8*)(aB + ((n * 4 + kc) * 2 + 1) * 512);
    }
  };
  auto blend_write = [&]() {
#pragma unroll
    for (int i = 0; i < 4; ++i) {
      bf16x8 ov;
#pragma unroll
      for (int e = 0; e < 8; ++e) {
        float f = G[i][0] * (float)C[i][0][e] + G[i][1] * (float)C[i][1][e] +
                  G[i][2] * (float)C[i][2][e] + G[i][3] * (float)C[i][3][e];
        ov[e] = (__bf16)f;
      }
      *(bf16x8*)(buf + (i * 8 + pxg) * TCS + slot * 16) = ov;
    }
  };
  auto consume = [&]() {
#pragma unroll
    for (int kc = 0; kc < 4; ++kc) {
      bf16x8 b0 = *(const bf16x8*)(bB + kc * 32);
      acc[0] = mfma32(a[kc * 2 + 0], b0, acc[0]);
      acc[1] = mfma32(a[kc * 2 + 1], b0, acc[1]);
    }
  };

  load_tap(n0);
  blend_write();
  for (int t = 1; t < nn; ++t) {
    load_a(n0 + t - 1);
    load_tap(n0 + t);
    consume();
    asm volatile("s_waitcnt lgkmcnt(0)" ::: "memory");
    blend_write();
  }
  load_a(n0 + nn - 1);
  consume();
  __syncthreads();               // all taps done; reuse smem for merge
  if (wid) merge_write(acc, smem + (wid - 1) * 8192);
  __syncthreads();
  if (wid == 0) {
    merge_add(acc, smem);
    merge_add(acc, smem + 8192);
    merge_add(acc, smem + 16384);
    __builtin_amdgcn_s_waitcnt(0);
    unsigned char* reg = smem;
    acc32_to_lds(acc, reg);
    __builtin_amdgcn_s_waitcnt(0);
    int colb = m, ch = half * 32;
    size_t pix = (size_t)b * HW + (size_t)h * 192 + w0 + colb;
    float* dp = xlow + pix * 64 + ch;
    __bf16* dpb = xlowb + pix * 64 + ch;
#pragma unroll
    for (int q = 0; q < 8; ++q) {
      f32x4 v = *(const f32x4*)(reg + (colb * 68 + ch + q * 4) * 4);
      *(f32x4*)(dp + q * 4) = v;
      bf16x4 o8;
#pragma unroll
      for (int e = 0; e < 4; ++e) o8[e] = (__bf16)v[e];
      *(bf16x4*)(dpb + q * 4) = o8;
    }
  }
}

// ---------------- convcat: 4-wave (ot x tap-group), glds-staged swizzled LDS ----
__global__ __launch_bounds__(256, 2) void convcat_mfma(
    const __bf16* __restrict__ xlowb, const __bf16* __restrict__ frn,
    const __bf16* __restrict__ wA, const float* __restrict__ bias,
    const __bf16* __restrict__ zpad, __bf16* __restrict__ y) {
  __shared__ __align__(16) unsigned char smem[2 * 4 * TROW];  // 40960
  int bid = (blockIdx.x & 7) * 144 + (blockIdx.x >> 3);
  int b = bid / 576, r = bid % 576, rt = r / 6, ct = r % 6;
  int h0 = rt * 2, w0 = ct * 32;
  int tid = threadIdx.x, wid = tid >> 6, lane = tid & 63;
  int ot = wid & 1, g = wid >> 1;
  int m = lane & 31, half = lane >> 5;
  const __bf16* src0 = xlowb + (size_t)b * HW * 64;
  const __bf16* src1 = frn + (size_t)b * HW * 64;
  for (int o = wid; o < 40; o += 4) {
    int t = o / 20, rr = (o % 20) / 5, ck = o % 5;
    stage_glds(t ? src1 : src0, 192, 192, h0 - 1 + rr, w0 - 1, zpad,
               smem + t * (4 * TROW) + rr * TROW, ck);
  }
  __syncthreads();
  const __bf16* aB = wA + lane * 8;
  const unsigned char* tile = smem + g * (4 * TROW);
  int koff = g ? 4 : 0;
  f32x16 acc[2];
  acc[0] = zero16(); acc[1] = zero16();
#pragma unroll
  for (int n = 0; n < 9; ++n) tapG<8>(aB, ot, tile, n, koff, acc);
  __syncthreads();
  if (g == 1) merge_write(acc, smem + ot * 8192);
  __syncthreads();
  if (g == 0) merge_add(acc, smem + ot * 8192);
  __syncthreads();
  if (g == 0) {
    treg_write(acc[0], ot, smem);
    treg_write(acc[1], ot, smem + TREG);
  }
  __syncthreads();
  if (g == 0) {
    const unsigned char* reg = smem + ot * TREG;
    int ch = half * 32;
    int row = h0 + ot;
    __bf16* dp = y + ((size_t)b * HW + (size_t)row * 192 + w0 + m) * 64 + ch;
#pragma unroll
    for (int q = 0; q < 8; ++q) {
      f32x4 v = *(const f32x4*)(reg + (m * 68 + ch + q * 4) * 4);
      v += *(const f32x4*)(bias + ch + q * 4);
      bf16x4 o8;
#pragma unroll
      for (int e = 0; e < 4; ++e) o8[e] = (__bf16)v[e];
      *(bf16x4*)(dp + q * 4) = o8;
    }
  }
}

// ---------------- conv1 + GDN + CELU: 4-wave, glds-staged ----------------
__global__ __launch_bounds__(256, 2) void conv1gdn_mfma(
    const __bf16* __restrict__ y, const __bf16* __restrict__ w1A,
    const __bf16* __restrict__ gA, const float* __restrict__ beta,
    const __bf16* __restrict__ zpad, __bf16* __restrict__ hbuf) {
  __shared__ __align__(16) unsigned char smem[9216 + 2 * TREG];  // 26624 >= tile 20480
  int bid = (blockIdx.x & 7) * 144 + (blockIdx.x >> 3);
  int b = bid / 576, r = bid % 576, rt = r / 6, ct = r % 6;
  int h0 = rt * 2, w0 = ct * 32;
  int tid = threadIdx.x, wid = tid >> 6, lane = tid & 63;
  int ot = wid & 1, g = wid >> 1;
  int m = lane & 31, half = lane >> 5, kh8 = half << 3;
  const __bf16* src = y + (size_t)b * HW * 64;
  for (int o = wid; o < 20; o += 4) {
    int rr = o / 5, ck = o % 5;
    stage_glds(src, 192, 192, h0 + rr, w0, zpad, smem + rr * TROW, ck);
  }
  __syncthreads();
  const __bf16* aB = w1A + lane * 8;
  f32x16 acc[2];
  acc[0] = zero16(); acc[1] = zero16();
  int n0 = g ? 5 : 0, nn = g ? 4 : 5;
  for (int t = 0; t < nn; ++t) tapG<4>(aB, ot, smem, n0 + t, 0, acc);
  __syncthreads();
  if (g == 1) merge_write(acc, smem + ot * 8192);
  __syncthreads();
  if (g == 0) merge_add(acc, smem + ot * 8192);
  __syncthreads();
  // v^2 tile [64px][64ch] at smem (only g0 waves hold data)
  unsigned char* gdnreg = smem;
  if (g == 0) {
#pragma unroll
    for (int pt = 0; pt < 2; ++pt)
#pragma unroll
      for (int gg = 0; gg < 4; ++gg) {
        int o = ot * 32 + half * 4 + gg * 8;
        int p = pt * 32 + m;
        bf16x4 s;
#pragma unroll
        for (int e = 0; e < 4; ++e) {
          float x = acc[pt][gg * 4 + e];
          s[e] = (__bf16)(x * x);
        }
        *(bf16x4*)(gdnreg + p * GDNPITCH + o * 2) = s;
      }
  }
  __syncthreads();
  if (g == 0) {
    f32x16 nacc[2];
    nacc[0] = zero16(); nacc[1] = zero16();
    const __bf16* gaB = gA + lane * 8;
    const unsigned char* gb = gdnreg + m * GDNPITCH + kh8 * 2;
#pragma unroll
    for (int kc = 0; kc < 4; ++kc) {
      bf16x8 ga = *(const bf16x8*)(gaB + (kc * 2 + ot) * 512);
      bf16x8 b0 = *(const bf16x8*)(gb + kc * 32);
      bf16x8 b1 = *(const bf16x8*)(gb + 32 * GDNPITCH + kc * 32);
      nacc[0] = mfma32(ga, b0, nacc[0]);
      nacc[1] = mfma32(ga, b1, nacc[1]);
    }
#pragma unroll
    for (int gg = 0; gg < 4; ++gg) {
      f32x4 bet = *(const f32x4*)(beta + ot * 32 + half * 4 + gg * 8);
#pragma unroll
      for (int pt = 0; pt < 2; ++pt)
#pragma unroll
        for (int e = 0; e < 4; ++e) {
          float nv = bet[e] + nacc[pt][gg * 4 + e];
          float hv = acc[pt][gg * 4 + e] * rsqrtf(nv);
          hv = hv > 0.f ? hv : expf(hv) - 1.f;
          acc[pt][gg * 4 + e] = hv;
        }
    }
  }
  __syncthreads();
  if (g == 0) {
    treg_write(acc[0], ot, smem);
    treg_write(acc[1], ot, smem + TREG);
  }
  __syncthreads();
  if (g == 0) {
    const unsigned char* reg = smem + ot * TREG;
    int ch = half * 32;
    int hr = h0 + ot, wcol = w0 + m;
    if (hr < 190 && wcol < 190) {
      __bf16* dp = hbuf + ((size_t)b * HW1 + (size_t)hr * 190 + wcol) * 64 + ch;
#pragma unroll
      for (int q = 0; q < 8; ++q) {
        f32x4 v = *(const f32x4*)(reg + (m * 68 + ch + q * 4) * 4);
        bf16x4 o8;
#pragma unroll
        for (int e = 0; e < 4; ++e) o8[e] = (__bf16)v[e];
        *(bf16x4*)(dp + q * 4) = o8;
      }
    }
  }
}

// ---------------- conv2 (pad 2) + residual: 4-wave, glds-staged ----------------
template <bool LAST>
__global__ __launch_bounds__(256, 2) void conv2_mfma(
    const __bf16* __restrict__ hbuf, const __bf16* __restrict__ w2A,
    const float* __restrict__ xlow, const __bf16* __restrict__ zpad,
    __bf16* __restrict__ y, float* __restrict__ out) {
  __shared__ __align__(16) unsigned char smem[4 * TROW];  // 20480
  int bid = (blockIdx.x & 7) * 144 + (blockIdx.x >> 3);
  int b = bid / 576, r = bid % 576, rt = r / 6, ct = r % 6;
  int h0 = rt * 2, w0 = ct * 32;
  int tid = threadIdx.x, wid = tid >> 6, lane = tid & 63;
  int ot = wid & 1, g = wid >> 1;
  int m = lane & 31, half = lane >> 5;
  const __bf16* src = hbuf + (size_t)b * HW1 * 64;
  for (int o = wid; o < 20; o += 4) {
    int rr = o / 5, ck = o % 5;
    stage_glds(src, 190, 190, h0 - 2 + rr, w0 - 2, zpad, smem + rr * TROW, ck);
  }
  __syncthreads();
  const __bf16* aB = w2A + lane * 8;
  f32x16 acc[2];
  acc[0] = zero16(); acc[1] = zero16();
  int n0 = g ? 5 : 0, nn = g ? 4 : 5;
  for (int t = 0; t < nn; ++t) tapG<4>(aB, ot, smem, n0 + t, 0, acc);
  __syncthreads();
  if (g == 1) merge_write(acc, smem + ot * 8192);
  __syncthreads();
  if (g == 0) merge_add(acc, smem + ot * 8192);
  __syncthreads();
  if (g == 0) {
    treg_write(acc[0], ot, smem);
    treg_write(acc[1], ot, smem + TREG);
  }
  __syncthreads();
  if (g == 0) {
    unsigned char* reg = smem + ot * TREG;
    int ch = half * 32;
    int row = h0 + ot;
    size_t pix = (size_t)b * HW + (size_t)row * 192 + w0 + m;
    __bf16* yp = y + pix * 64 + ch;
    f32x4 v[8];
#pragma unroll
    for (int q = 0; q < 8; ++q) {
      v[q] = *(const f32x4*)(reg + (m * 68 + ch + q * 4) * 4);
      bf16x4 yv = *(const bf16x4*)(yp + q * 4);
#pragma unroll
      for (int e = 0; e < 4; ++e) v[q][e] += (float)yv[e];
    }
    if (!LAST) {
#pragma unroll
      for (int q = 0; q < 8; ++q) {
        bf16x4 o8;
#pragma unroll
        for (int e = 0; e < 4; ++e) o8[e] = (__bf16)v[q][e];
        *(bf16x4*)(yp + q * 4) = o8;
      }
    } else {
      const float* xp = xlow + pix * 64 + ch;
#pragma unroll
      for (int q = 0; q < 8; ++q) v[q] += *(const f32x4*)(xp + q * 4);
#pragma unroll
      for (int q = 0; q < 8; ++q)
        *(f32x4*)(reg + (m * 68 + ch + q * 4) * 4) = v[q];
      __builtin_amdgcn_s_waitcnt(0);
      int o = lane;
      float* op = out + ((size_t)b * 64 + o) * HW + (size_t)row * 192 + w0;
#pragma unroll
      for (int q = 0; q < 8; ++q) {
        f32x4 s;
#pragma unroll
        for (int e = 0; e < 4; ++e)
          s[e] = *(const float*)(reg + ((q * 4 + e) * 68 + o) * 4);
        *(f32x4*)(op + q * 4) = s;
      }
    }
  }
}

extern "C" void kernel_launch(void* const* d_in, const int* in_sizes, int n_in,
                              void* d_out, int out_size, void* d_ws, size_t ws_size,
                              hipStream_t stream) {
  const float* f_r      = (const float*)d_in[0];
  const float* m_t      = (const float*)d_in[1];
  const float* w_pconv  = (const float*)d_in[2];
  const float* b_pconv  = (const float*)d_in[3];
  const float* w_dc     = (const float*)d_in[4];
  const float* w_cat    = (const float*)d_in[5];
  const float* b_cat    = (const float*)d_in[6];
  const float* rb_w1    = (const float*)d_in[7];
  const float* rb_w2    = (const float*)d_in[8];
  const float* rb_beta  = (const float*)d_in[9];
  const float* rb_gamma = (const float*)d_in[10];
  float* out = (float*)d_out;

  float* ws = (float*)d_ws;
  float*  xlow  = ws;                         // [2][HW][64] f32 (residual x)
  __bf16* ybuf  = (__bf16*)(xlow + 4718592);  // [2][HW][64] bf16
  __bf16* xlowb = (__bf16*)(xlow + 4718592 + 2359296);  // [2][HW][64] bf16 (x as bf16)
  float*  off20 = xlow + 4718592 + 4718592;   // [2][HW][20] f32
  __bf16* frn   = (__bf16*)(off20 + 1474560); // [2][HW][64] bf16
  __bf16* mtn   = (__bf16*)(off20 + 1474560 + 2359296);
  __bf16* hbuf  = mtn;                        // mtn dead after pconv
  float*  wbase = off20 + 1474560 + 2359296 + 2359296;
  __bf16* wpA   = (__bf16*)wbase;
  __bf16* wdcA  = (__bf16*)(wbase + 9216);
  __bf16* wcatA = (__bf16*)(wbase + 27648);
  __bf16* w1A   = (__bf16*)(wbase + 64512);
  __bf16* w2A   = (__bf16*)(wbase + 119808);
  __bf16* gA    = (__bf16*)(wbase + 175104);
  float*  bpad  = wbase + 181248;
  const __bf16* zpad = (const __bf16*)(bpad + 32);  // 256B zero page

  prep_and_nhwc<<<NPREP + 2304, 256, 0, stream>>>(
      w_pconv, b_pconv, w_dc, w_cat, rb_w1, rb_w2, rb_gamma,
      wpA, wdcA, wcatA, w1A, w2A, gA, bpad, f_r, m_t, frn, mtn);
  pconv_mfma<<<288, 256, 0, stream>>>(mtn, wpA, bpad, off20);
  deform_mfma<<<2304, 256, 0, stream>>>(frn, off20, wdcA, xlow, xlowb);
  convcat_mfma<<<1152, 256, 0, stream>>>(xlowb, frn, wcatA, b_cat, zpad, ybuf);
  for (int l = 0; l < 3; ++l) {
    conv1gdn_mfma<<<1152, 256, 0, stream>>>(ybuf, w1A + l * 36864, gA + l * 4096,
                                            rb_beta + l * 64, zpad, hbuf);
    if (l < 2)
      conv2_mfma<false><<<1152, 256, 0, stream>>>(hbuf, w2A + l * 36864, xlow, zpad, ybuf, out);
    else
      conv2_mfma<true><<<1152, 256, 0, stream>>>(hbuf, w2A + l * 36864, xlow, zpad, ybuf, out);
  }
}

// Round 9
// 258.033 us; speedup vs baseline: 1.0673x; 1.0673x over previous
//
#include <hip/hip_runtime.h>

typedef __attribute__((ext_vector_type(8))) __bf16 bf16x8;
typedef __attribute__((ext_vector_type(4))) __bf16 bf16x4;
typedef __attribute__((ext_vector_type(16))) float f32x16;
typedef __attribute__((ext_vector_type(4))) float f32x4;
typedef __attribute__((ext_vector_type(4))) int i32x4;

#define HH 192
#define WW 192
#define HW 36864
#define HW1 36100

#define TCS 144                  // deform/pconv staged col pitch
#define RP66 (66 * TCS)          // pconv staging row pitch
#define GDNPITCH 144
#define TREG 8704                // transpose region: 32 px x 68 f32
#define TROW 5120                // tail-kernel LDS row pitch: 40 cols x 128B
#define NPREP 1417               // prep blocks in fused prologue kernel

__device__ inline f32x16 mfma32(bf16x8 a, bf16x8 b, f32x16 c) {
  return __builtin_amdgcn_mfma_f32_32x32x16_bf16(a, b, c, 0, 0, 0);
}

__device__ inline f32x16 zero16() {
  f32x16 z;
#pragma unroll
  for (int e = 0; e < 16; ++e) z[e] = 0.f;
  return z;
}

// ---------------- fused prologue: weight prep + NCHW->NHWC transpose ----------------
__global__ __launch_bounds__(256) void prep_and_nhwc(
    const float* __restrict__ wp, const float* __restrict__ bp,
    const float* __restrict__ wdc, const float* __restrict__ wcat,
    const float* __restrict__ w1, const float* __restrict__ w2,
    const float* __restrict__ gamma,
    __bf16* __restrict__ wpA, __bf16* __restrict__ wdcA,
    __bf16* __restrict__ wcatA, __bf16* __restrict__ w1A,
    __bf16* __restrict__ w2A, __bf16* __restrict__ gA,
    float* __restrict__ bpad,
    const float* __restrict__ fr, const float* __restrict__ mt,
    __bf16* __restrict__ frn, __bf16* __restrict__ mtn) {
  __shared__ __align__(16) __bf16 tile[64 * 72];
  if (blockIdx.x >= NPREP) {
    // -------- transpose path --------
    int rem2 = blockIdx.x - NPREP;
    int tensor = rem2 / 1152, rem = rem2 % 1152;
    int b = rem / 576, p0 = (rem % 576) * 64;
    const float* src = (tensor ? mt : fr) + (size_t)b * 64 * HW;
    __bf16* dst = (tensor ? mtn : frn) + (size_t)b * HW * 64;
    int tid = threadIdx.x, c = tid >> 2, q0 = (tid & 3) * 16;
    const float* sp = src + (size_t)c * HW + p0 + q0;
#pragma unroll
    for (int qq = 0; qq < 4; ++qq) {
      f32x4 v = *(const f32x4*)(sp + qq * 4);
#pragma unroll
      for (int e = 0; e < 4; ++e) tile[(q0 + qq * 4 + e) * 72 + c] = (__bf16)v[e];
    }
    __syncthreads();
    int px = tid >> 2, c0 = (tid & 3) * 16;
    bf16x8 a = *(const bf16x8*)(&tile[px * 72 + c0]);
    bf16x8 b8 = *(const bf16x8*)(&tile[px * 72 + c0 + 8]);
    __bf16* dp = dst + (size_t)(p0 + px) * 64 + c0;
    *(bf16x8*)dp = a;
    *(bf16x8*)(dp + 8) = b8;
    return;
  }
  // -------- weight-prep path --------
  int i = blockIdx.x * 256 + threadIdx.x;
  if (i < 18432) {
    int j = i & 7, lane = (i >> 3) & 63, kc = (i >> 9) & 3, n = i >> 11;
    int o = lane & 31, c = kc * 16 + ((lane >> 5) << 3) + j;
    wpA[i] = (o < 18) ? (__bf16)wp[(o * 64 + c) * 9 + n] : (__bf16)0.f;
    return;
  }
  i -= 18432;
  if (i < 36864) {
    int j = i & 7, lane = (i >> 3) & 63, ot = (i >> 9) & 1, kc = (i >> 10) & 3, n = i >> 12;
    int o = ot * 32 + (lane & 31), c = kc * 16 + ((lane >> 5) << 3) + j;
    wdcA[i] = (__bf16)wdc[(o * 64 + c) * 9 + n];
    return;
  }
  i -= 36864;
  if (i < 73728) {
    int d = i, j = d & 7; d >>= 3; int lane = d & 63; d >>= 6; int ot = d & 1; d >>= 1;
    int kc = d & 7; int n = d >> 3;
    int o = ot * 32 + (lane & 31), c = kc * 16 + ((lane >> 5) << 3) + j;
    wcatA[i] = (__bf16)wcat[(o * 128 + c) * 9 + n];
    return;
  }
  i -= 73728;
  if (i < 110592) {
    int l = i / 36864, di = i % 36864, d = di;
    int j = d & 7; d >>= 3; int lane = d & 63; d >>= 6; int ot = d & 1; d >>= 1;
    int kc = d & 3; int n = d >> 2;
    int o = ot * 32 + (lane & 31), c = kc * 16 + ((lane >> 5) << 3) + j;
    w1A[l * 36864 + di] = (__bf16)w1[l * 36864 + (o * 64 + c) * 9 + n];
    return;
  }
  i -= 110592;
  if (i < 110592) {
    int l = i / 36864, di = i % 36864, d = di;
    int j = d & 7; d >>= 3; int lane = d & 63; d >>= 6; int ot = d & 1; d >>= 1;
    int kc = d & 3; int n = d >> 2;
    int o = ot * 32 + (lane & 31), c = kc * 16 + ((lane >> 5) << 3) + j;
    w2A[l * 36864 + di] = (__bf16)w2[l * 36864 + (o * 64 + c) * 9 + n];
    return;
  }
  i -= 110592;
  if (i < 12288) {
    int l = i / 4096, di = i % 4096, d = di;
    int j = d & 7; d >>= 3; int lane = d & 63; d >>= 6; int ot = d & 1; d >>= 1;
    int kc = d & 3;
    int o = ot * 32 + (lane & 31), c = kc * 16 + ((lane >> 5) << 3) + j;
    gA[l * 4096 + di] = (__bf16)gamma[l * 4096 + o * 64 + c];
    return;
  }
  i -= 12288;
  // bpad[0..17] = pconv bias, bpad[18..95] = 0 (incl. 256B zero page at +32)
  if (i < 96) bpad[i] = (i < 18) ? bp[i] : 0.f;
}

// ---------------- staging loop (pconv only) ----------------
template <int ROWS, int COLS, int TPB>
__device__ inline void stage_bf16T(const __bf16* __restrict__ src,
                                   int srcH, int srcW, int row0, int col0,
                                   unsigned char* lds) {
  for (int i = threadIdx.x; i < ROWS * COLS * 8; i += TPB) {
    int r = i / (COLS * 8), rem = i - r * (COLS * 8), j = rem >> 3, u = rem & 7;
    int gr = row0 + r, gc = col0 + j;
    bf16x8 v;
#pragma unroll
    for (int e = 0; e < 8; ++e) v[e] = (__bf16)0.f;
    if (gr >= 0 && gr < srcH && gc >= 0 && gc < srcW)
      v = *(const bf16x8*)(src + ((size_t)gr * srcW + gc) * 64 + u * 8);
    *(bf16x8*)(lds + r * (COLS * TCS) + j * TCS + u * 16) = v;
  }
}

// ---- global_load_lds staging of one 1KB chunk (8 cols x 8 granules) ----
__device__ inline void stage_glds(const __bf16* __restrict__ src, int H, int W,
                                  int gr, int gc0, const __bf16* __restrict__ zpad,
                                  unsigned char* ldsrow, int chunk) {
  int l = threadIdx.x & 63;
  int colg = l >> 3, gsrc = (l & 7) ^ colg;
  int gc = gc0 + chunk * 8 + colg;
  const __bf16* gp = zpad;
  if (gr >= 0 && gr < H && gc >= 0 && gc < W)
    gp = src + ((size_t)gr * W + gc) * 64 + gsrc * 8;
  __builtin_amdgcn_global_load_lds(
      (const __attribute__((address_space(1))) void*)gp,
      (__attribute__((address_space(3))) void*)(ldsrow + chunk * 1024), 16, 0, 0);
}

// ---- per-wave tap: wave (pt,ot) = 32 out-ch x 32 px of row h0+pt ----
template <int KCW>
__device__ inline void tapG1(const __bf16* __restrict__ aB, int ot, int pt,
                             const unsigned char* __restrict__ tile,
                             int n, int koff, f32x16& acc) {
  int lane = threadIdx.x & 63;
  int m = lane & 31, half = lane >> 5;
  int kh = n / 3, kw = n % 3;
  int p = kw + m, p7 = p & 7;
  bf16x8 A[4], B[4];
#pragma unroll
  for (int kc = 0; kc < 4; ++kc)
    A[kc] = *(const bf16x8*)(aB + (size_t)((n * KCW + koff + kc) * 2 + ot) * 512);
#pragma unroll
  for (int kc = 0; kc < 4; ++kc) {
    int gsl = ((kc * 2 + half) ^ p7) << 4;
    B[kc] = *(const bf16x8*)(tile + (kh + pt) * TROW + p * 128 + gsl);
  }
#pragma unroll
  for (int kc = 0; kc < 4; ++kc) acc = mfma32(A[kc], B[kc], acc);
}

// ---- epilogue: write one row's (ot-half) acc into a shared transpose region ----
__device__ inline void treg_write(const f32x16& a, int ot, unsigned char* reg) {
  int lane = threadIdx.x & 63;
  int m = lane & 31, half = lane >> 5;
#pragma unroll
  for (int g = 0; g < 4; ++g) {
    int o = ot * 32 + half * 4 + g * 8;
    f32x4 v;
    v[0] = a[g * 4 + 0]; v[1] = a[g * 4 + 1];
    v[2] = a[g * 4 + 2]; v[3] = a[g * 4 + 3];
    *(f32x4*)(reg + (m * 68 + o) * 4) = v;
  }
}

// ---- deform merge helpers (XOR-swizzled, bank-conflict-free) ----
__device__ inline void merge_write(const f32x16 acc[2], unsigned char* mb) {
  int l = threadIdx.x & 63;
  unsigned char* p = mb + l * 128;
#pragma unroll
  for (int pt = 0; pt < 2; ++pt)
#pragma unroll
    for (int i = 0; i < 4; ++i) {
      f32x4 v;
      v[0] = acc[pt][i * 4 + 0]; v[1] = acc[pt][i * 4 + 1];
      v[2] = acc[pt][i * 4 + 2]; v[3] = acc[pt][i * 4 + 3];
      *(f32x4*)(p + (((pt * 4 + i) ^ (l & 7)) * 16)) = v;
    }
}
__device__ inline void merge_add(f32x16 acc[2], const unsigned char* mb) {
  int l = threadIdx.x & 63;
  const unsigned char* p = mb + l * 128;
#pragma unroll
  for (int pt = 0; pt < 2; ++pt)
#pragma unroll
    for (int i = 0; i < 4; ++i) {
      f32x4 v = *(const f32x4*)(p + (((pt * 4 + i) ^ (l & 7)) * 16));
      acc[pt][i * 4 + 0] += v[0]; acc[pt][i * 4 + 1] += v[1];
      acc[pt][i * 4 + 2] += v[2]; acc[pt][i * 4 + 3] += v[3];
    }
}

// ---------------- deform epilogue helper ----------------
__device__ inline void acc32_to_lds(const f32x16 acc[2], unsigned char* reg) {
  int lane = threadIdx.x & 63;
  int colb = lane & 31, half = lane >> 5;
#pragma unroll
  for (int ot = 0; ot < 2; ++ot)
#pragma unroll
    for (int g = 0; g < 4; ++g) {
      int o = ot * 32 + half * 4 + g * 8;
      f32x4 v;
      v[0] = acc[ot][g * 4 + 0]; v[1] = acc[ot][g * 4 + 1];
      v[2] = acc[ot][g * 4 + 2]; v[3] = acc[ot][g * 4 + 3];
      *(f32x4*)(reg + (colb * 68 + o) * 4) = v;
    }
}

// ---------------- pconv MFMA (unchanged) ----------------
__global__ __launch_bounds__(256, 1) void pconv_mfma(
    const __bf16* __restrict__ mtn, const __bf16* __restrict__ wpA,
    const float* __restrict__ bpad, float* __restrict__ off20) {
  __shared__ __align__(16) unsigned char smem[6 * RP66];
  int b = blockIdx.x / 144, r = blockIdx.x % 144, rt = r / 3, ct = r % 3;
  int h0 = rt * 4, w0 = ct * 64;
  int wid = threadIdx.x >> 6, lane = threadIdx.x & 63;
  int colb = lane & 31, half = lane >> 5, kh8 = half << 3;
  stage_bf16T<6, 66, 256>(mtn + (size_t)b * HW * 64, 192, 192, h0 - 1, w0 - 1, smem);
  const __bf16* aB = wpA + lane * 8;
  bf16x8 pcur[4], pnxt[4];
#pragma unroll
  for (int kc = 0; kc < 4; ++kc) pcur[kc] = *(const bf16x8*)(aB + kc * 512);
  __syncthreads();
  f32x16 acc[2];
  acc[0] = zero16(); acc[1] = zero16();
  {
    const unsigned char* bB = smem + wid * RP66 + colb * TCS + kh8 * 2;
#pragma unroll
    for (int n = 0; n < 9; ++n) {
      if (n < 8) {
#pragma unroll
        for (int kc = 0; kc < 4; ++kc)
          pnxt[kc] = *(const bf16x8*)(aB + ((n + 1) * 4 + kc) * 512);
      }
      const int kh = n / 3, kw = n % 3;
#pragma unroll
      for (int kc = 0; kc < 4; ++kc) {
        const unsigned char* bp = bB + kh * RP66 + kw * TCS + kc * 32;
        bf16x8 b0 = *(const bf16x8*)(bp);
        bf16x8 b1 = *(const bf16x8*)(bp + 32 * TCS);
        acc[0] = mfma32(pcur[kc], b0, acc[0]);
        acc[1] = mfma32(pcur[kc], b1, acc[1]);
      }
#pragma unroll
      for (int kc = 0; kc < 4; ++kc) pcur[kc] = pnxt[kc];
    }
  }
  __syncthreads();
  unsigned char* reg = smem + wid * 9216;
#pragma unroll
  for (int pt = 0; pt < 2; ++pt)
#pragma unroll
    for (int g = 0; g < 4; ++g) {
      int o = half * 4 + g * 8;
      f32x4 v;
      v[0] = acc[pt][g * 4 + 0]; v[1] = acc[pt][g * 4 + 1];
      v[2] = acc[pt][g * 4 + 2]; v[3] = acc[pt][g * 4 + 3];
      *(f32x4*)(reg + ((pt * 32 + colb) * 36 + o) * 4) = v;
    }
  __builtin_amdgcn_s_waitcnt(0);
  size_t pix = (size_t)b * HW + (size_t)(h0 + wid) * 192 + w0 + lane;
#pragma unroll
  for (int q = 0; q < 5; ++q) {
    f32x4 v = *(const f32x4*)(reg + (lane * 36 + q * 4) * 4);
    v += *(const f32x4*)(bpad + q * 4);
    *(f32x4*)(off20 + pix * 20 + q * 4) = v;
  }
}

// ---------------- deformable conv: 4-wave tap-split + XOR LDS merge ----------------
#define GOPITCH 32
#define DTBL (9 * 32 * GOPITCH)   // 9216: g/idx table
#define DBUF 4608                 // 32 px x TCS blended tile per wave
#define DLDS (DTBL + 4 * DBUF)    // 27648
__global__ __launch_bounds__(256, 2) void deform_mfma(
    const __bf16* __restrict__ frn, const float* __restrict__ off20,
    const __bf16* __restrict__ wdcA, float* __restrict__ xlow,
    __bf16* __restrict__ xlowb) {
  __shared__ __align__(16) unsigned char smem[DLDS];
  int bid = (blockIdx.x & 7) * 288 + (blockIdx.x >> 3);
  int b = bid / 1152, r = bid % 1152;
  int h = r / 6, s = r % 6;
  int w0 = s * 32;
  int tid = threadIdx.x;
  int wid = tid >> 6, lane = tid & 63;
  int m = lane & 31, half = lane >> 5;
  int pxg = lane >> 3, slot = lane & 7;
  const __bf16* xb = frn + (size_t)b * HW * 64;
  // ---- offset prologue: 256 threads, 9 taps x 32 px ----
  {
    int px = tid & 31, g = tid >> 5;   // g = 0..7
    int w = w0 + px;
    size_t pixl = (size_t)b * HW + (size_t)h * 192 + w;
    const float* ofp = off20 + pixl * 20;
    for (int n = g; n < 9; n += 8) {
      float offr = ofp[n], offc = ofp[9 + n];
      float pr = (float)(h + 1 + n / 3 - 1) + offr;
      float pc = (float)(w + 1 + n % 3 - 1) + offc;
      float prc = fminf(fmaxf(pr, 0.f), 193.f);
      float pcc = fminf(fmaxf(pc, 0.f), 193.f);
      float f0r = floorf(pr), f0c = floorf(pc);
      int qr0 = (int)fminf(fmaxf(f0r, 0.f), 193.f);
      int qc0 = (int)fminf(fmaxf(f0c, 0.f), 193.f);
      int qr1 = (int)fminf(fmaxf(f0r + 1.f, 0.f), 193.f);
      int qc1 = (int)fminf(fmaxf(f0c + 1.f, 0.f), 193.f);
      float dr0 = 1.f + ((float)qr0 - prc);
      float dr1 = 1.f - ((float)qr1 - prc);
      float dc0 = 1.f + ((float)qc0 - pcc);
      float dc1 = 1.f - ((float)qc1 - pcc);
      int o0, o1, o2, o3; float g0, g1, g2, g3;
      { bool v = (qr0 >= 1 && qr0 <= 192 && qc0 >= 1 && qc0 <= 192);
        o0 = min(max(qr0-1,0),191)*WW + min(max(qc0-1,0),191); g0 = v ? dr0*dc0 : 0.f; }
      { bool v = (qr1 >= 1 && qr1 <= 192 && qc1 >= 1 && qc1 <= 192);
        o1 = min(max(qr1-1,0),191)*WW + min(max(qc1-1,0),191); g1 = v ? dr1*dc1 : 0.f; }
      { bool v = (qr0 >= 1 && qr0 <= 192 && qc1 >= 1 && qc1 <= 192);
        o2 = min(max(qr0-1,0),191)*WW + min(max(qc1-1,0),191); g2 = v ? dr0*dc1 : 0.f; }
      { bool v = (qr1 >= 1 && qr1 <= 192 && qc0 >= 1 && qc0 <= 192);
        o3 = min(max(qr1-1,0),191)*WW + min(max(qc0-1,0),191); g3 = v ? dr1*dc0 : 0.f; }
      unsigned char* dst = smem + (n * 32 + px) * GOPITCH;
      f32x4 gv; gv[0] = g0; gv[1] = g1; gv[2] = g2; gv[3] = g3;
      i32x4 ov; ov[0] = o0; ov[1] = o1; ov[2] = o2; ov[3] = o3;
      *(f32x4*)dst = gv;
      *(i32x4*)(dst + 16) = ov;
    }
  }
  __syncthreads();
  f32x16 acc[2];
  acc[0] = zero16(); acc[1] = zero16();
  const __bf16* aB = wdcA + lane * 8;
  unsigned char* buf = smem + DTBL + wid * DBUF;
  const unsigned char* bB = buf + m * TCS + (half << 3) * 2;
  // tap split: wave0: 0-2, wave1: 3-4, wave2: 5-6, wave3: 7-8
  int n0 = (wid == 0) ? 0 : (wid * 2 + 1);
  int nn = (wid == 0) ? 3 : 2;

  bf16x8 C[4][4];
  f32x4 G[4];
  bf16x8 a[8];

  auto load_tap = [&](int n) {
#pragma unroll
    for (int i = 0; i < 4; ++i) {
      const unsigned char* gp = smem + (size_t)(n * 32 + i * 8 + pxg) * GOPITCH;
      i32x4 oi = *(const i32x4*)(gp + 16);
      G[i] = *(const f32x4*)gp;
#pragma unroll
      for (int j = 0; j < 4; ++j)
        C[i][j] = *(const bf16x8*)(xb + (size_t)oi[j] * 64 + slot * 8);
    }
  };
  auto load_a = [&](int n) {
#pragma unroll
    for (int kc = 0; kc < 4; ++kc) {
      a[kc * 2 + 0] = *(const bf16x8*)(aB + ((n * 4 + kc) * 2 + 0) * 512);
      a[kc * 2 + 1] = *(const bf16x8*)(aB + ((n * 4 + kc) * 2 + 1) * 512);
    }
  };
  auto blend_write = [&]() {
#pragma unroll
    for (int i = 0; i < 4; ++i) {
      bf16x8 ov;
#pragma unroll
      for (int e = 0; e < 8; ++e) {
        float f = G[i][0] * (float)C[i][0][e] + G[i][1] * (float)C[i][1][e] +
                  G[i][2] * (float)C[i][2][e] + G[i][3] * (float)C[i][3][e];
        ov[e] = (__bf16)f;
      }
      *(bf16x8*)(buf + (i * 8 + pxg) * TCS + slot * 16) = ov;
    }
  };
  auto consume = [&]() {
#pragma unroll
    for (int kc = 0; kc < 4; ++kc) {
      bf16x8 b0 = *(const bf16x8*)(bB + kc * 32);
      acc[0] = mfma32(a[kc * 2 + 0], b0, acc[0]);
      acc[1] = mfma32(a[kc * 2 + 1], b0, acc[1]);
    }
  };

  load_tap(n0);
  blend_write();
  for (int t = 1; t < nn; ++t) {
    load_a(n0 + t - 1);
    load_tap(n0 + t);
    consume();
    asm volatile("s_waitcnt lgkmcnt(0)" ::: "memory");
    blend_write();
  }
  load_a(n0 + nn - 1);
  consume();
  __syncthreads();               // all taps done; reuse smem for merge
  if (wid) merge_write(acc, smem + (wid - 1) * 8192);
  __syncthreads();
  if (wid == 0) {
    merge_add(acc, smem);
    merge_add(acc, smem + 8192);
    merge_add(acc, smem + 16384);
    __builtin_amdgcn_s_waitcnt(0);
    unsigned char* reg = smem;
    acc32_to_lds(acc, reg);
    __builtin_amdgcn_s_waitcnt(0);
    int colb = m, ch = half * 32;
    size_t pix = (size_t)b * HW + (size_t)h * 192 + w0 + colb;
    float* dp = xlow + pix * 64 + ch;
    __bf16* dpb = xlowb + pix * 64 + ch;
#pragma unroll
    for (int q = 0; q < 8; ++q) {
      f32x4 v = *(const f32x4*)(reg + (colb * 68 + ch + q * 4) * 4);
      *(f32x4*)(dp + q * 4) = v;
      bf16x4 o8;
#pragma unroll
      for (int e = 0; e < 4; ++e) o8[e] = (__bf16)v[e];
      *(bf16x4*)(dpb + q * 4) = o8;
    }
  }
}

// ---------------- convcat: 4-wave (pt,ot) quadrants, no merge ----------------
__global__ __launch_bounds__(256, 4) void convcat_mfma(
    const __bf16* __restrict__ xlowb, const __bf16* __restrict__ frn,
    const __bf16* __restrict__ wA, const float* __restrict__ bias,
    const __bf16* __restrict__ zpad, __bf16* __restrict__ y) {
  __shared__ __align__(16) unsigned char smem[2 * 4 * TROW];  // 40960
  int bid = (blockIdx.x & 7) * 144 + (blockIdx.x >> 3);
  int b = bid / 576, r = bid % 576, rt = r / 6, ct = r % 6;
  int h0 = rt * 2, w0 = ct * 32;
  int tid = threadIdx.x, wid = tid >> 6, lane = tid & 63;
  int pt = wid & 1, ot = wid >> 1;
  int m = lane & 31, half = lane >> 5;
  const __bf16* src0 = xlowb + (size_t)b * HW * 64;
  const __bf16* src1 = frn + (size_t)b * HW * 64;
  for (int o = wid; o < 40; o += 4) {
    int t = o / 20, rr = (o % 20) / 5, ck = o % 5;
    stage_glds(t ? src1 : src0, 192, 192, h0 - 1 + rr, w0 - 1, zpad,
               smem + t * (4 * TROW) + rr * TROW, ck);
  }
  __syncthreads();
  const __bf16* aB = wA + lane * 8;
  f32x16 acc = zero16();
#pragma unroll
  for (int n = 0; n < 9; ++n) tapG1<8>(aB, ot, pt, smem, n, 0, acc);
#pragma unroll
  for (int n = 0; n < 9; ++n) tapG1<8>(aB, ot, pt, smem + 4 * TROW, n, 4, acc);
  __syncthreads();
  treg_write(acc, ot, smem + pt * TREG);
  __syncthreads();
  {
    const unsigned char* reg = smem + pt * TREG;
    int ch = ot * 32 + half * 16;
    int row = h0 + pt;
    __bf16* dp = y + ((size_t)b * HW + (size_t)row * 192 + w0 + m) * 64 + ch;
#pragma unroll
    for (int q = 0; q < 4; ++q) {
      f32x4 v = *(const f32x4*)(reg + (m * 68 + ch + q * 4) * 4);
      v += *(const f32x4*)(bias + ch + q * 4);
      bf16x4 o8;
#pragma unroll
      for (int e = 0; e < 4; ++e) o8[e] = (__bf16)v[e];
      *(bf16x4*)(dp + q * 4) = o8;
    }
  }
}

// ---------------- conv1 + GDN + CELU: 4-wave (pt,ot), no merge ----------------
__global__ __launch_bounds__(256, 4) void conv1gdn_mfma(
    const __bf16* __restrict__ y, const __bf16* __restrict__ w1A,
    const __bf16* __restrict__ gA, const float* __restrict__ beta,
    const __bf16* __restrict__ zpad, __bf16* __restrict__ hbuf) {
  __shared__ __align__(16) unsigned char smem[9216 + 2 * TREG];  // 26624 >= tile 20480
  int bid = (blockIdx.x & 7) * 144 + (blockIdx.x >> 3);
  int b = bid / 576, r = bid % 576, rt = r / 6, ct = r % 6;
  int h0 = rt * 2, w0 = ct * 32;
  int tid = threadIdx.x, wid = tid >> 6, lane = tid & 63;
  int pt = wid & 1, ot = wid >> 1;
  int m = lane & 31, half = lane >> 5, kh8 = half << 3;
  const __bf16* src = y + (size_t)b * HW * 64;
  for (int o = wid; o < 20; o += 4) {
    int rr = o / 5, ck = o % 5;
    stage_glds(src, 192, 192, h0 + rr, w0, zpad, smem + rr * TROW, ck);
  }
  __syncthreads();
  const __bf16* aB = w1A + lane * 8;
  f32x16 acc = zero16();
#pragma unroll
  for (int n = 0; n < 9; ++n) tapG1<4>(aB, ot, pt, smem, n, 0, acc);
  __syncthreads();   // tile reads done; reuse smem for gdn tile
  // v^2 tile [64px][64ch]; each wave writes its (pt,ot) quadrant
  unsigned char* gdnreg = smem;
  {
    int p = pt * 32 + m;
#pragma unroll
    for (int gg = 0; gg < 4; ++gg) {
      int o = ot * 32 + half * 4 + gg * 8;
      bf16x4 s;
#pragma unroll
      for (int e = 0; e < 4; ++e) {
        float x = acc[gg * 4 + e];
        s[e] = (__bf16)(x * x);
      }
      *(bf16x4*)(gdnreg + p * GDNPITCH + o * 2) = s;
    }
  }
  __syncthreads();
  {
    f32x16 nacc = zero16();
    const __bf16* gaB = gA + lane * 8;
    const unsigned char* gb = gdnreg + (pt * 32 + m) * GDNPITCH + kh8 * 2;
#pragma unroll
    for (int kc = 0; kc < 4; ++kc) {
      bf16x8 ga = *(const bf16x8*)(gaB + (kc * 2 + ot) * 512);
      bf16x8 b0 = *(const bf16x8*)(gb + kc * 32);
      nacc = mfma32(ga, b0, nacc);
    }
#pragma unroll
    for (int gg = 0; gg < 4; ++gg) {
      f32x4 bet = *(const f32x4*)(beta + ot * 32 + half * 4 + gg * 8);
#pragma unroll
      for (int e = 0; e < 4; ++e) {
        float nv = bet[e] + nacc[gg * 4 + e];
        float hv = acc[gg * 4 + e] * rsqrtf(nv);
        hv = hv > 0.f ? hv : expf(hv) - 1.f;
        acc[gg * 4 + e] = hv;
      }
    }
  }
  // treg region (smem+9216..) does not overlap gdn tile (0..9216): no barrier needed
  treg_write(acc, ot, smem + 9216 + pt * TREG);
  __syncthreads();
  {
    const unsigned char* reg = smem + 9216 + pt * TREG;
    int ch = ot * 32 + half * 16;
    int hr = h0 + pt, wcol = w0 + m;
    if (hr < 190 && wcol < 190) {
      __bf16* dp = hbuf + ((size_t)b * HW1 + (size_t)hr * 190 + wcol) * 64 + ch;
#pragma unroll
      for (int q = 0; q < 4; ++q) {
        f32x4 v = *(const f32x4*)(reg + (m * 68 + ch + q * 4) * 4);
        bf16x4 o8;
#pragma unroll
        for (int e = 0; e < 4; ++e) o8[e] = (__bf16)v[e];
        *(bf16x4*)(dp + q * 4) = o8;
      }
    }
  }
}

// ---------------- conv2 (pad 2) + residual: 4-wave (pt,ot), no merge ----------------
template <bool LAST>
__global__ __launch_bounds__(256, 4) void conv2_mfma(
    const __bf16* __restrict__ hbuf, const __bf16* __restrict__ w2A,
    const float* __restrict__ xlow, const __bf16* __restrict__ zpad,
    __bf16* __restrict__ y, float* __restrict__ out) {
  __shared__ __align__(16) unsigned char smem[4 * TROW];  // 20480 >= 2*TREG
  int bid = (blockIdx.x & 7) * 144 + (blockIdx.x >> 3);
  int b = bid / 576, r = bid % 576, rt = r / 6, ct = r % 6;
  int h0 = rt * 2, w0 = ct * 32;
  int tid = threadIdx.x, wid = tid >> 6, lane = tid & 63;
  int pt = wid & 1, ot = wid >> 1;
  int m = lane & 31, half = lane >> 5;
  const __bf16* src = hbuf + (size_t)b * HW1 * 64;
  for (int o = wid; o < 20; o += 4) {
    int rr = o / 5, ck = o % 5;
    stage_glds(src, 190, 190, h0 - 2 + rr, w0 - 2, zpad, smem + rr * TROW, ck);
  }
  __syncthreads();
  const __bf16* aB = w2A + lane * 8;
  f32x16 acc = zero16();
#pragma unroll
  for (int n = 0; n < 9; ++n) tapG1<4>(aB, ot, pt, smem, n, 0, acc);
  __syncthreads();
  treg_write(acc, ot, smem + pt * TREG);
  __syncthreads();
  {
    unsigned char* reg = smem + pt * TREG;
    int ch = ot * 32 + half * 16;
    int row = h0 + pt;
    size_t pix = (size_t)b * HW + (size_t)row * 192 + w0 + m;
    __bf16* yp = y + pix * 64 + ch;
    f32x4 v[4];
#pragma unroll
    for (int q = 0; q < 4; ++q) {
      v[q] = *(const f32x4*)(reg + (m * 68 + ch + q * 4) * 4);
      bf16x4 yv = *(const bf16x4*)(yp + q * 4);
#pragma unroll
      for (int e = 0; e < 4; ++e) v[q][e] += (float)yv[e];
    }
    if (!LAST) {
#pragma unroll
      for (int q = 0; q < 4; ++q) {
        bf16x4 o8;
#pragma unroll
        for (int e = 0; e < 4; ++e) o8[e] = (__bf16)v[q][e];
        *(bf16x4*)(yp + q * 4) = o8;
      }
    } else {
      const float* xp = xlow + pix * 64 + ch;
#pragma unroll
      for (int q = 0; q < 4; ++q) v[q] += *(const f32x4*)(xp + q * 4);
#pragma unroll
      for (int q = 0; q < 4; ++q)
        *(f32x4*)(reg + (m * 68 + ch + q * 4) * 4) = v[q];
      __syncthreads();
      // NCHW store: wave (pt,ot): channel = lane, px quarter by ot
      int o = lane;
      float* op = out + ((size_t)b * 64 + o) * HW + (size_t)row * 192 + w0;
#pragma unroll
      for (int qq = 0; qq < 4; ++qq) {
        int q = ot * 4 + qq;
        f32x4 s;
#pragma unroll
        for (int e = 0; e < 4; ++e)
          s[e] = *(const float*)(reg + ((q * 4 + e) * 68 + o) * 4);
        *(f32x4*)(op + q * 4) = s;
      }
    }
  }
}

extern "C" void kernel_launch(void* const* d_in, const int* in_sizes, int n_in,
                              void* d_out, int out_size, void* d_ws, size_t ws_size,
                              hipStream_t stream) {
  const float* f_r      = (const float*)d_in[0];
  const float* m_t      = (const float*)d_in[1];
  const float* w_pconv  = (const float*)d_in[2];
  const float* b_pconv  = (const float*)d_in[3];
  const float* w_dc     = (const float*)d_in[4];
  const float* w_cat    = (const float*)d_in[5];
  const float* b_cat    = (const float*)d_in[6];
  const float* rb_w1    = (const float*)d_in[7];
  const float* rb_w2    = (const float*)d_in[8];
  const float* rb_beta  = (const float*)d_in[9];
  const float* rb_gamma = (const float*)d_in[10];
  float* out = (float*)d_out;

  float* ws = (float*)d_ws;
  float*  xlow  = ws;                         // [2][HW][64] f32 (residual x)
  __bf16* ybuf  = (__bf16*)(xlow + 4718592);  // [2][HW][64] bf16
  __bf16* xlowb = (__bf16*)(xlow + 4718592 + 2359296);  // [2][HW][64] bf16 (x as bf16)
  float*  off20 = xlow + 4718592 + 4718592;   // [2][HW][20] f32
  __bf16* frn   = (__bf16*)(off20 + 1474560); // [2][HW][64] bf16
  __bf16* mtn   = (__bf16*)(off20 + 1474560 + 2359296);
  __bf16* hbuf  = mtn;                        // mtn dead after pconv
  float*  wbase = off20 + 1474560 + 2359296 + 2359296;
  __bf16* wpA   = (__bf16*)wbase;
  __bf16* wdcA  = (__bf16*)(wbase + 9216);
  __bf16* wcatA = (__bf16*)(wbase + 27648);
  __bf16* w1A   = (__bf16*)(wbase + 64512);
  __bf16* w2A   = (__bf16*)(wbase + 119808);
  __bf16* gA    = (__bf16*)(wbase + 175104);
  float*  bpad  = wbase + 181248;
  const __bf16* zpad = (const __bf16*)(bpad + 32);  // 256B zero page

  prep_and_nhwc<<<NPREP + 2304, 256, 0, stream>>>(
      w_pconv, b_pconv, w_dc, w_cat, rb_w1, rb_w2, rb_gamma,
      wpA, wdcA, wcatA, w1A, w2A, gA, bpad, f_r, m_t, frn, mtn);
  pconv_mfma<<<288, 256, 0, stream>>>(mtn, wpA, bpad, off20);
  deform_mfma<<<2304, 256, 0, stream>>>(frn, off20, wdcA, xlow, xlowb);
  convcat_mfma<<<1152, 256, 0, stream>>>(xlowb, frn, wcatA, b_cat, zpad, ybuf);
  for (int l = 0; l < 3; ++l) {
    conv1gdn_mfma<<<1152, 256, 0, stream>>>(ybuf, w1A + l * 36864, gA + l * 4096,
                                            rb_beta + l * 64, zpad, hbuf);
    if (l < 2)
      conv2_mfma<false><<<1152, 256, 0, stream>>>(hbuf, w2A + l * 36864, xlow, zpad, ybuf, out);
    else
      conv2_mfma<true><<<1152, 256, 0, stream>>>(hbuf, w2A + l * 36864, xlow, zpad, ybuf, out);
  }
}